// Round 5
// baseline (30.966 us; speedup 1.0000x reference)
//
#include <hip/hip_runtime.h>

#define N2 128
#define BLOCK 256        // 4 waves; wave w covers j in [32w, 32w+32)
#define APB 128          // anchors per block: 2 per lane (i and i+64)
#define BAND 9.5367431640625e-07f   // 2^-20 relative guard band

__global__ __launch_bounds__(BLOCK, 8) void matcher_kernel(
    const float4* __restrict__ boxes1,
    const float4* __restrict__ boxes2,
    float* __restrict__ out_vals,
    float* __restrict__ out_idx,
    float* __restrict__ out_labels,
    int n1)
{
#pragma clang fp contract(off)
    __shared__ float4 s_b2[N2];
    __shared__ float  s_area2[N2];
    __shared__ float  s_q[4][APB];
    __shared__ int    s_ix[4][APB];

    const int t = threadIdx.x;
    if (t < N2) {
        const float4 b = boxes2[t];            // (y1, x1, y2, x2)
        s_b2[t] = b;
        s_area2[t] = (b.z - b.x) * (b.w - b.y);
    }
    __syncthreads();

    const int w    = __builtin_amdgcn_readfirstlane(t >> 6); // wave id, uniform
    const int lane = t & 63;
    const int i0   = blockIdx.x * APB + lane;
    const int i1   = i0 + 64;

    const float4 a0 = boxes1[(i0 < n1) ? i0 : 0];
    const float4 a1 = boxes1[(i1 < n1) ? i1 : 0];
    const float ar0 = (a0.z - a0.x) * (a0.w - a0.y);
    const float ar1 = (a1.z - a1.x) * (a1.w - a1.y);

    const int j0 = w * 32;
    float bq0 = -1.0f, bq1 = -1.0f;
    int   bx0 = j0,    bx1 = j0;
    bool  slow = false;

#pragma unroll 2
    for (int k = 0; k < 32; ++k) {
        const int j = j0 + k;                  // wave-uniform
        const float4 b = s_b2[j];              // uniform ds_read -> broadcast
        const float a2 = s_area2[j];           // uniform ds_read -> broadcast
        // anchor 0
        {
            const float hy = fmaxf(fminf(a0.z, b.z) - fmaxf(a0.x, b.x), 0.0f);
            const float hx = fmaxf(fminf(a0.w, b.w) - fmaxf(a0.y, b.y), 0.0f);
            const float inter = hy * hx;
            const float um = fmaxf((ar0 + a2) - inter, 1e-10f);
            const float q = inter * __builtin_amdgcn_rcpf(um);
            const float d = q - bq0;
            const float th = bq0 * BAND;
            slow = slow | ((inter > 0.0f) & (fabsf(d) <= th));
            if (d > th) { bq0 = q; bx0 = j; }
        }
        // anchor 1
        {
            const float hy = fmaxf(fminf(a1.z, b.z) - fmaxf(a1.x, b.x), 0.0f);
            const float hx = fmaxf(fminf(a1.w, b.w) - fmaxf(a1.y, b.y), 0.0f);
            const float inter = hy * hx;
            const float um = fmaxf((ar1 + a2) - inter, 1e-10f);
            const float q = inter * __builtin_amdgcn_rcpf(um);
            const float d = q - bq1;
            const float th = bq1 * BAND;
            slow = slow | ((inter > 0.0f) & (fabsf(d) <= th));
            if (d > th) { bq1 = q; bx1 = j; }
        }
    }

#define FRAC(J, AA, AR, INTER, UM)                                    \
    {                                                                 \
        const float4 b = s_b2[(J)];                                   \
        const float hy = fmaxf(fminf(AA.z, b.z) - fmaxf(AA.x, b.x), 0.0f); \
        const float hx = fmaxf(fminf(AA.w, b.w) - fmaxf(AA.y, b.y), 0.0f); \
        INTER = hy * hx;                                              \
        UM = fmaxf(((AR) + s_area2[(J)]) - INTER, 1e-10f);            \
    }

    if (slow) {
        // rare: replay this wave's window with exact reference semantics
        float b0 = -1.0f, b1 = -1.0f;
        int   x0 = j0,    x1 = j0;
        for (int k = 0; k < 32; ++k) {
            const int j = j0 + k;
            float in0, um0, in1, um1;
            FRAC(j, a0, ar0, in0, um0)
            FRAC(j, a1, ar1, in1, um1)
            const float q0 = in0 / um0;
            const float q1 = in1 / um1;
            if (q0 > b0) { b0 = q0; x0 = j; }
            if (q1 > b1) { b1 = q1; x1 = j; }
        }
        bx0 = x0; bx1 = x1;
    }

    // one exact IEEE divide per winner reproduces matched_val bitwise
    float qe0, qe1;
    {
        float in0, um0, in1, um1;
        FRAC(bx0, a0, ar0, in0, um0)
        FRAC(bx1, a1, ar1, in1, um1)
        qe0 = in0 / um0;
        qe1 = in1 / um1;
    }

    s_q[w][lane]       = qe0;
    s_ix[w][lane]      = bx0;
    s_q[w][lane + 64]  = qe1;
    s_ix[w][lane + 64] = bx1;
    __syncthreads();

    // merge the 4 wave-partials; ascending wave + strict > == first-max
    if (t < APB) {
        const int ii = blockIdx.x * APB + t;
        if (ii < n1) {
            float q  = s_q[0][t];
            int   ix = s_ix[0][t];
#pragma unroll
            for (int w2 = 1; w2 < 4; ++w2) {
                const float q2 = s_q[w2][t];
                if (q2 > q) { q = q2; ix = s_ix[w2][t]; }
            }
            out_vals[ii]   = q;
            out_idx[ii]    = (float)ix;
            out_labels[ii] = (q >= 0.7f) ? 1.0f : ((q < 0.3f) ? 0.0f : -1.0f);
        }
    }
}

extern "C" void kernel_launch(void* const* d_in, const int* in_sizes, int n_in,
                              void* d_out, int out_size, void* d_ws, size_t ws_size,
                              hipStream_t stream) {
    const float4* boxes1 = (const float4*)d_in[0];
    const float4* boxes2 = (const float4*)d_in[1];
    const int n1 = in_sizes[0] / 4;

    float* out = (float*)d_out;
    float* out_vals   = out;
    float* out_idx    = out + n1;
    float* out_labels = out + 2 * n1;

    const int grid = (n1 + APB - 1) / APB;
    matcher_kernel<<<grid, BLOCK, 0, stream>>>(boxes1, boxes2,
                                               out_vals, out_idx, out_labels, n1);
}